// Round 11
// baseline (266.981 us; speedup 1.0000x reference)
//
#include <hip/hip_runtime.h>
#include <hip/hip_bf16.h>
#include <cmath>
#include <cstdint>

// ---------------------------------------------------------------------------
// QuantumTransformerBlock. Inputs f32, output f32. Internals bf16 MFMA.
// R20: gemm8 deepened to 3-buffer rotation (2 tiles in flight, vmcnt(12)
//      steady-state -> prefetch issued ~600cy before use, wait ~free).
//      LDS 72KB, still 2 blocks/CU. Tail drains 6->0. Everything else
//      byte-identical to R19 (attn/qkvvt8 floors proven).
// ---------------------------------------------------------------------------

typedef __bf16 bf16_t;
typedef __bf16 bf16x8 __attribute__((ext_vector_type(8)));
typedef float f32x4 __attribute__((ext_vector_type(4)));
typedef unsigned short u16x4 __attribute__((ext_vector_type(4)));

#define DEV_INLINE __device__ __forceinline__
#define MB 1048576

DEV_INLINE void gload16(const void* g, void* lds) {
  __builtin_amdgcn_global_load_lds(
      (const __attribute__((address_space(1))) unsigned int*)g,
      (__attribute__((address_space(3))) unsigned int*)lds, 16, 0, 0);
}

DEV_INLINE unsigned short bf16_bits(float f) {
  bf16_t b = (bf16_t)f;
  return __builtin_bit_cast(unsigned short, b);
}

#define BAR_PRE_LGKM asm volatile("s_waitcnt lgkmcnt(0)" ::: "memory")
#define BAR_PRE_VM8 asm volatile("s_waitcnt vmcnt(8)" ::: "memory")
#define RAW_BAR                 \
  __builtin_amdgcn_s_barrier(); \
  asm volatile("" ::: "memory")

// ---------------------------------------------------------------------------
// prep: [0,2048) convx  x f32 -> bf16 (f32x4 vector loads)
//       [2048,5120) tconv3 wq|wk|wv -> wqkvT[3072][1024]
//       [5120,8192) tconv3 wo|w1|w2 -> wT3[3072][1024]
// ---------------------------------------------------------------------------
__global__ __launch_bounds__(256) void prep_kernel(
    const float* __restrict__ x, const float* __restrict__ wq,
    const float* __restrict__ wk, const float* __restrict__ wv,
    const float* __restrict__ wo, const float* __restrict__ w1,
    const float* __restrict__ w2, bf16_t* __restrict__ xc,
    bf16_t* __restrict__ wqkvT, bf16_t* __restrict__ wT3) {
  __shared__ bf16_t t[32][36];  // row stride 72B: u16x4 8B-aligned
  const int bid = blockIdx.x;
  if (bid < 2048) {
    const size_t i0 = ((size_t)bid * 256 + threadIdx.x) * 8;
    const f32x4 a = *(const f32x4*)&x[i0];
    const f32x4 b2 = *(const f32x4*)&x[i0 + 4];
    bf16x8 v;
#pragma unroll
    for (int j = 0; j < 4; ++j) {
      v[j] = (bf16_t)a[j];
      v[4 + j] = (bf16_t)b2[j];
    }
    *(bf16x8*)(xc + i0) = v;
    return;
  }
  const int grp = (bid - 2048) / 3072;  // 0 -> wqkvT, 1 -> wT3
  const int tcb = (bid - 2048) - grp * 3072;
  const int mi = tcb >> 10;
  const float* src;
  bf16_t* dst;
  if (grp == 0) {
    src = (mi == 0) ? wq : (mi == 1) ? wk : wv;
    dst = wqkvT;
  } else {
    src = (mi == 0) ? wo : (mi == 1) ? w1 : w2;
    dst = wT3;
  }
  const int rem = tcb & 1023;
  const int bx = (rem & 31) * 32, by = (rem >> 5) * 32;
  const int r = threadIdx.x >> 3, g4 = (threadIdx.x & 7) * 4;

  const f32x4 v4 = *(const f32x4*)&src[(size_t)(by + r) * 1024 + bx + g4];
  u16x4 w4;
#pragma unroll
  for (int e = 0; e < 4; ++e) w4[e] = bf16_bits(v4[e]);
  *(u16x4*)&t[r][g4] = w4;
  __syncthreads();

  u16x4 o4;
#pragma unroll
  for (int e = 0; e < 4; ++e)
    o4[e] = __builtin_bit_cast(unsigned short, t[g4 + e][r]);
  *(u16x4*)&dst[(size_t)(mi * 1024 + bx + r) * 1024 + by + g4] = o4;
}

// ---------------------------------------------------------------------------
// merged QK + VT GEMM, 256x256-tile coarse 2-phase pipeline (R11 version).
// blocks [0,128): QK  C[4096 x 2048] = xc @ (wq|wk)T^T   (16 x 8 tiles)
// blocks [128,192): VT C[1024 x 4096] = wvT @ xc^T       (4 x 16 tiles)
// 512 threads = 8 waves (2M x 4N), per-wave 128x64 output, BK=64.
// Swizzle: logical byte p stored at p ^ (((p>>7)&7)<<4) (involution).
// ---------------------------------------------------------------------------
DEV_INLINE void stage_tile(const char* __restrict__ G, char* ldsT, int k0b,
                           int wid, int lane) {
#pragma unroll
  for (int t = 0; t < 4; ++t) {
    const int plin = t * 8192 + wid * 1024 + lane * 16;
    const int p = plin ^ ((((unsigned)plin >> 7) & 7) << 4);
    gload16(G + (size_t)(p >> 7) * 2048 + k0b + (p & 127),
            ldsT + t * 8192 + wid * 1024);
  }
}

DEV_INLINE void compute_tile(const char* lds_tile, int wm, int wn, int quad,
                             int tc, f32x4 (&acc)[8][4]) {
  const char* Ab = lds_tile;
  const char* Bb = lds_tile + 32768;
#pragma unroll
  for (int ks = 0; ks < 2; ++ks) {
    const int colb = ks * 64 + quad * 16;
    bf16x8 bfv[4];
#pragma unroll
    for (int j = 0; j < 4; ++j) {
      const int r = wn + j * 16 + tc;
      bfv[j] = *(const bf16x8*)(Bb + ((r * 128 + colb) ^ ((r & 7) << 4)));
    }
#pragma unroll
    for (int ih = 0; ih < 2; ++ih) {
      bf16x8 af[4];
#pragma unroll
      for (int i = 0; i < 4; ++i) {
        const int r = wm + (ih * 4 + i) * 16 + tc;
        af[i] = *(const bf16x8*)(Ab + ((r * 128 + colb) ^ ((r & 7) << 4)));
      }
      __builtin_amdgcn_s_setprio(1);
#pragma unroll
      for (int i = 0; i < 4; ++i)
#pragma unroll
        for (int j = 0; j < 4; ++j)
          acc[ih * 4 + i][j] = __builtin_amdgcn_mfma_f32_16x16x32_bf16(
              af[i], bfv[j], acc[ih * 4 + i][j], 0, 0, 0);
      __builtin_amdgcn_s_setprio(0);
    }
  }
}

__global__ __launch_bounds__(512, 2) void qkvvt8_kernel(
    const bf16_t* __restrict__ xc, const bf16_t* __restrict__ wqkvT,
    bf16_t* __restrict__ qb, bf16_t* __restrict__ kb,
    bf16_t* __restrict__ vTb) {
  __shared__ __align__(16) char lds[131072];
  const int tid = threadIdx.x, wid = tid >> 6, lane = tid & 63;
  const int quad = lane >> 4, tc = lane & 15;
  const int bid = blockIdx.x;
  const int isqk = (bid < 128);
  int m0, n0;
  const char *A, *B;
  if (isqk) {
    m0 = (bid >> 3) * 256;
    n0 = (bid & 7) * 256;
    A = (const char*)(xc + (size_t)m0 * 1024);
    B = (const char*)(wqkvT + (size_t)n0 * 1024);
  } else {
    const int t2 = bid - 128;
    m0 = (t2 >> 4) * 256;
    n0 = (t2 & 15) * 256;
    A = (const char*)(wqkvT + (size_t)(2 * 1024 * 1024) + (size_t)m0 * 1024);
    B = (const char*)(xc + (size_t)n0 * 1024);
  }
  const int wm = (wid >> 2) * 128, wn = (wid & 3) * 64;

  f32x4 acc[8][4] = {};

  stage_tile(A, lds, 0, wid, lane);
  stage_tile(B, lds + 32768, 0, wid, lane);
  stage_tile(A, lds + 65536, 128, wid, lane);
  stage_tile(B, lds + 98304, 128, wid, lane);
  BAR_PRE_VM8;
  RAW_BAR;

  for (int it = 0; it < 7; ++it) {
    const int k0b = it * 256 + 256;
    compute_tile(lds, wm, wn, quad, tc, acc);
    BAR_PRE_LGKM;
    RAW_BAR;
    stage_tile(A, lds, k0b, wid, lane);
    stage_tile(B, lds + 32768, k0b, wid, lane);
    BAR_PRE_VM8;
    RAW_BAR;
    compute_tile(lds + 65536, wm, wn, quad, tc, acc);
    BAR_PRE_LGKM;
    RAW_BAR;
    stage_tile(A, lds + 65536, k0b + 128, wid, lane);
    stage_tile(B, lds + 98304, k0b + 128, wid, lane);
    BAR_PRE_VM8;
    RAW_BAR;
  }
  compute_tile(lds, wm, wn, quad, tc, acc);
  asm volatile("s_waitcnt vmcnt(0)" ::: "memory");
  BAR_PRE_LGKM;
  RAW_BAR;
  compute_tile(lds + 65536, wm, wn, quad, tc, acc);

#pragma unroll
  for (int i = 0; i < 8; ++i) {
#pragma unroll
    for (int j = 0; j < 4; ++j) {
      const int row0 = m0 + wm + i * 16 + quad * 4;
      const int col = n0 + wn + j * 16 + tc;
      if (isqk) {
        const int part = col >> 10, e = col & 1023, hh = e >> 6, d = e & 63;
        bf16_t* dst = part ? kb : qb;
#pragma unroll
        for (int r = 0; r < 4; ++r) {
          const int row = row0 + r;
          const int b = row >> 11, s = row & 2047;
          dst[((size_t)(b * 16 + hh) * 2048 + s) * 64 + d] = (bf16_t)acc[i][j][r];
        }
      } else {
        const int b = col >> 11, s = col & 2047;
#pragma unroll
        for (int r = 0; r < 4; ++r) {
          vTb[((size_t)(b * 1024 + row0 + r)) * 2048 + s] = (bf16_t)acc[i][j][r];
        }
      }
    }
  }
}

// ---------------------------------------------------------------------------
// W-GEMM R20: C[4096,1024] = A[4096,1024] * Bt[1024,1024]^T.
// BM=64, BN=128, BK=64, 256 threads = 4 waves (2x2), per-wave 32x64 output.
// 3-BUFFER rotation (LDS 72KB = 3 x (A 8KB + B 16KB)) -> 2 tiles in
// flight; steady-state vmcnt(12) = tile t+1 landed (issued 2 phases /
// ~600cy earlier -> wait ~free). Tail: vmcnt(6) -> vmcnt(0).
// Grid 512 = 64 m-tiles x 8 n-tiles, XCD-chunked; 2 blocks/CU (144KB).
// ---------------------------------------------------------------------------
enum { EPI_WO = 2, EPI_W1 = 3, EPI_W2 = 4 };

DEV_INLINE void stageA64(const char* __restrict__ G, char* ldsT, int k0b,
                         int tid) {
#pragma unroll
  for (int t = 0; t < 2; ++t) {
    const int plin = t * 4096 + tid * 16;
    const int p = plin ^ ((((unsigned)plin >> 7) & 7) << 4);
    gload16(G + (size_t)(p >> 7) * 2048 + k0b + (p & 127),
            ldsT + t * 4096 + (tid >> 6) * 1024);
  }
}

DEV_INLINE void stageB128(const char* __restrict__ G, char* ldsT, int k0b,
                          int tid) {
#pragma unroll
  for (int t = 0; t < 4; ++t) {
    const int plin = t * 4096 + tid * 16;
    const int p = plin ^ ((((unsigned)plin >> 7) & 7) << 4);
    gload16(G + (size_t)(p >> 7) * 2048 + k0b + (p & 127),
            ldsT + t * 4096 + (tid >> 6) * 1024);
  }
}

DEV_INLINE void compute64(const char* lds_tile, int wm, int wn, int quad,
                          int tc, f32x4 (&acc)[2][4]) {
  const char* Ab = lds_tile;
  const char* Bb = lds_tile + 8192;
#pragma unroll
  for (int ks = 0; ks < 2; ++ks) {
    const int colb = ks * 64 + quad * 16;
    bf16x8 bfv[4];
#pragma unroll
    for (int j = 0; j < 4; ++j) {
      const int r = wn + j * 16 + tc;
      bfv[j] = *(const bf16x8*)(Bb + ((r * 128 + colb) ^ ((r & 7) << 4)));
    }
    bf16x8 af[2];
#pragma unroll
    for (int i = 0; i < 2; ++i) {
      const int r = wm + i * 16 + tc;
      af[i] = *(const bf16x8*)(Ab + ((r * 128 + colb) ^ ((r & 7) << 4)));
    }
    __builtin_amdgcn_s_setprio(1);
#pragma unroll
    for (int i = 0; i < 2; ++i)
#pragma unroll
      for (int j = 0; j < 4; ++j)
        acc[i][j] = __builtin_amdgcn_mfma_f32_16x16x32_bf16(af[i], bfv[j],
                                                            acc[i][j], 0, 0, 0);
    __builtin_amdgcn_s_setprio(0);
  }
}

template <int EPI>
__global__ __launch_bounds__(256, 2) void gemm8_kernel(
    const bf16_t* __restrict__ A, const bf16_t* __restrict__ Bt,
    void* __restrict__ o0, const float* __restrict__ auxf,
    const bf16_t* __restrict__ auxb, const float* __restrict__ bias,
    const float* __restrict__ scal) {
  __shared__ __align__(16) char lds[73728];  // 3 x 24KB
  const int tid = threadIdx.x, wid = tid >> 6, lane = tid & 63;
  const int quad = lane >> 4, tc = lane & 15;
  const int bid = blockIdx.x;
  const int g = (bid & 7) * 64 + (bid >> 3);  // XCD-chunked tile id
  const int m0 = (g >> 3) * 64, n0 = (g & 7) * 128;
  const char* Ag = (const char*)A + (size_t)m0 * 2048;
  const char* Bg = (const char*)Bt + (size_t)n0 * 2048;
  const int wm = (wid >> 1) * 32, wn = (wid & 1) * 64;

  f32x4 acc[2][4] = {};

  // prologue: stage tiles 0,1,2 -> bufs 0,1,2 (18 loads); vmcnt(12) = t0.
  stageA64(Ag, lds, 0, tid);
  stageB128(Bg, lds + 8192, 0, tid);
  stageA64(Ag, lds + 24576, 128, tid);
  stageB128(Bg, lds + 24576 + 8192, 128, tid);
  stageA64(Ag, lds + 49152, 256, tid);
  stageB128(Bg, lds + 49152 + 8192, 256, tid);
  asm volatile("s_waitcnt vmcnt(12)" ::: "memory");
  RAW_BAR;

  int cb = 0;
  for (int it = 0; it < 16; ++it) {
    char* buf = lds + cb * 24576;
    compute64(buf, wm, wn, quad, tc, acc);
    if (it == 15) break;
    BAR_PRE_LGKM;
    RAW_BAR;  // buf's ds_reads retired in all waves -> safe to restage
    if (it <= 12) {
      const int kt = (it + 3) * 128;  // byte col of tile it+3
      stageA64(Ag, buf, kt, tid);
      stageB128(Bg, buf + 8192, kt, tid);
      asm volatile("s_waitcnt vmcnt(12)" ::: "memory");  // t_{it+1} landed
    } else if (it == 13) {
      asm volatile("s_waitcnt vmcnt(6)" ::: "memory");  // t14 landed
    } else {  // it == 14
      asm volatile("s_waitcnt vmcnt(0)" ::: "memory");  // t15 landed
    }
    RAW_BAR;
    cb = (cb == 2) ? 0 : cb + 1;
  }

  float wsig = 0.f;
  if (EPI == EPI_W1) wsig = 1.f / (1.f + __expf(-scal[0]));

#pragma unroll
  for (int i = 0; i < 2; ++i) {
#pragma unroll
    for (int j = 0; j < 4; ++j) {
      const int row0 = m0 + wm + i * 16 + quad * 4;
      const int col = n0 + wn + j * 16 + tc;
      if (EPI == EPI_WO) {
#pragma unroll
        for (int r = 0; r < 4; ++r) {
          const int row = row0 + r;
          ((float*)o0)[(size_t)row * 1024 + col] =
              acc[i][j][r] + auxf[(size_t)row * 1024 + col];
        }
      } else if (EPI == EPI_W1) {
#pragma unroll
        for (int r = 0; r < 4; ++r) {
          const int row = row0 + r;
          float c = fmaxf(acc[i][j][r] + bias[col], 0.f);
          const float qv = (float)auxb[(size_t)row * 1024 + col];
          ((bf16_t*)o0)[(size_t)row * 1024 + col] =
              (bf16_t)(wsig * qv + (1.f - wsig) * c);
        }
      } else {  // EPI_W2
#pragma unroll
        for (int r = 0; r < 4; ++r) {
          const int row = row0 + r;
          ((float*)o0)[(size_t)row * 1024 + col] =
              acc[i][j][r] + bias[col] + (float)auxb[(size_t)row * 1024 + col];
        }
      }
    }
  }
}

// ---------------------------------------------------------------------------
// Flash attention (R11 structure): q-tile 128/block, 4 waves x 32 q-rows
// (2 subtiles). Register-prefetch K/V staging; exp2 softmax (no-max);
// S^T = K*Q^T; wave-local Ps. LDS strides 72.
// ---------------------------------------------------------------------------
__global__ __launch_bounds__(256) void attn_kernel(
    const bf16_t* __restrict__ q, const bf16_t* __restrict__ k,
    const bf16_t* __restrict__ vT, const float* __restrict__ aqw,
    bf16_t* __restrict__ out) {
  constexpr int S = 2048, LDK = 72;
  __shared__ __align__(16) bf16_t Ks[64 * LDK];
  __shared__ __align__(16) bf16_t Vs[64 * LDK];
  __shared__ __align__(16) bf16_t Ps[4][32 * LDK];
  __shared__ bf16_t Ql[128 * LDK];
  __shared__ float segp[128][4];

  const int tid = threadIdx.x, w = tid >> 6, lane = tid & 63;
  const int quad = lane >> 4, tc = lane & 15;
  const int bh = blockIdx.y, q0 = blockIdx.x * 128;
  const bf16_t* qg = q + ((size_t)bh * S + q0) * 64;
  const bf16_t* kg = k + (size_t)bh * S * 64;
  const bf16_t* vg = vT + (size_t)bh * 64 * S;

  const int strow = tid >> 2, stcol = (tid & 3) * 16;

  bf16x8 pk0 = *(const bf16x8*)(kg + (size_t)strow * 64 + stcol);
  bf16x8 pk1 = *(const bf16x8*)(kg + (size_t)strow * 64 + stcol + 8);
  bf16x8 pv0 = *(const bf16x8*)(vg + (size_t)strow * S + stcol);
  bf16x8 pv1 = *(const bf16x8*)(vg + (size_t)strow * S + stcol + 8);

  // quantum: cumprod(cos(q)) for 128 rows; 4 threads/row, 2 passes
  {
    float c[2][16];
    const int ss = tid & 3;
#pragma unroll
    for (int pass = 0; pass < 2; ++pass) {
      const int rr = pass * 64 + (tid >> 2);
      const bf16_t* qr = qg + rr * 64 + ss * 16;
      float p = 1.f;
#pragma unroll
      for (int j2 = 0; j2 < 16; ++j2) {
        c[pass][j2] = __cosf((float)qr[j2]);
        p *= c[pass][j2];
      }
      segp[rr][ss] = p;
    }
    __syncthreads();
#pragma unroll
    for (int pass = 0; pass < 2; ++pass) {
      const int rr = pass * 64 + (tid >> 2);
      float pre = 1.f;
      for (int u = 0; u < ss; ++u) pre *= segp[rr][u];
#pragma unroll
      for (int j2 = 0; j2 < 16; ++j2) {
        pre *= c[pass][j2];
        Ql[rr * LDK + ss * 16 + j2] = (bf16_t)pre;
      }
    }
  }

  bf16x8 aq[2][2];
#pragma unroll
  for (int qs = 0; qs < 2; ++qs) {
    const int qrow = w * 32 + qs * 16 + tc;
#pragma unroll
    for (int ks = 0; ks < 2; ++ks) {
      bf16x8 t = *(const bf16x8*)(qg + qrow * 64 + ks * 32 + quad * 8);
#pragma unroll
      for (int e = 0; e < 8; ++e) t[e] = (bf16_t)((float)t[e] * 0.18033688f);
      aq[qs][ks] = t;
    }
  }

  float lacc[2] = {0.f, 0.f};
  f32x4 o[2][4] = {};
  bf16_t* Pw = Ps[w];

  for (int kt = 0; kt < S; kt += 64) {
    __syncthreads();
    *(bf16x8*)&Ks[strow * LDK + stcol] = pk0;
    *(bf16x8*)&Ks[strow * LDK + stcol + 8] = pk1;
    *(bf16x8*)&Vs[strow * LDK + stcol] = pv0;
    *(bf16x8*)&Vs[strow * LDK + stcol + 8] = pv1;
    if (kt + 64 < S) {
      const int nk = kt + 64;
      pk0 = *(const bf16x8*)(kg + (size_t)(nk + strow) * 64 + stcol);
      pk1 = *(const bf16x8*)(kg + (size_t)(nk + strow) * 64 + stcol + 8);
      pv0 = *(const bf16x8*)(vg + (size_t)strow * S + nk + stcol);
      pv1 = *(const bf16x8*)(vg + (size_t)strow * S + nk + stcol + 8);
    }
    __syncthreads();

    f32x4 sf[2][4] = {};
#pragma unroll
    for (int ks = 0; ks < 2; ++ks) {
#pragma unroll
      for (int nt = 0; nt < 4; ++nt) {
        bf16x8 ak = *(const bf16x8*)&Ks[(nt * 16 + tc) * LDK + ks * 32 + quad * 8];
        sf[0][nt] = __builtin_amdgcn_mfma_f32_16x16x32_bf16(ak, aq[0][ks], sf[0][nt], 0, 0, 0);
        sf[1][nt] = __builtin_amdgcn_mfma_f32_16x16x32_bf16(ak, aq[1][ks], sf[1][nt], 0, 0, 0);
      }
    }

#pragma unroll
    for (int qs = 0; qs < 2; ++qs) {
#pragma unroll
      for (int nt = 0; nt < 4; ++nt) {
        u16x4 pk;
        float ps = 0.f;
#pragma unroll
        for (int r = 0; r < 4; ++r) {
          const float p = __builtin_amdgcn_exp2f(sf[qs][nt][r]);
          ps += p;
          pk[r] = bf16_bits(p);
        }
        lacc[qs] += ps;
        *(u16x4*)&Pw[(qs * 16 + tc) * LDK + nt * 16 + quad * 4] = pk;
      }
    }
    asm volatile("s_waitcnt lgkmcnt(0)" ::: "memory");

#pragma unroll
    for (int ks = 0; ks < 2; ++ks) {
      bf16x8 ap0 = *(const bf16x8*)&Pw[tc * LDK + ks * 32 + quad * 8];
      bf16x8 ap1 = *(const bf16x8*)&Pw[(16 + tc) * LDK + ks * 32 + quad * 8];
#pragma unroll
      for (int j = 0; j < 4; ++j) {
        bf16x8 bv = *(const bf16x8*)&Vs[(j * 16 + tc) * LDK + ks * 32 + quad * 8];
        o[0][j] = __builtin_amdgcn_mfma_f32_16x16x32_bf16(ap0, bv, o[0][j], 0, 0, 0);
        o[1][j] = __builtin_amdgcn_mfma_f32_16x16x32_bf16(ap1, bv, o[1][j], 0, 0, 0);
      }
    }
  }

#pragma unroll
  for (int qs = 0; qs < 2; ++qs) {
    lacc[qs] += __shfl_xor(lacc[qs], 16, 64);
    lacc[qs] += __shfl_xor(lacc[qs], 32, 64);
  }

  const float wsig = 1.f / (1.f + __expf(-aqw[0]));
  const int b = bh >> 4, h = bh & 15;
#pragma unroll
  for (int qs = 0; qs < 2; ++qs) {
#pragma unroll
    for (int r = 0; r < 4; ++r) {
      const int lr = quad * 4 + r;
      const float linv = 1.f / __shfl(lacc[qs], lr, 64);
      const int lrow = w * 32 + qs * 16 + lr;
      const int sg = q0 + lrow;
#pragma unroll
      for (int j = 0; j < 4; ++j) {
        const int d = j * 16 + tc;
        const float cl = o[qs][j][r] * linv;
        const float qv = (float)Ql[lrow * LDK + d];
        out[((size_t)(b * 2048 + sg)) * 1024 + h * 64 + d] =
            (bf16_t)(wsig * qv + (1.f - wsig) * cl);
      }
    }
  }
}

// ---------------------------------------------------------------------------
// LN1 + cumprod-scan fused: one block per row.
// ---------------------------------------------------------------------------
__global__ __launch_bounds__(256) void ln1scan_kernel(
    const float* __restrict__ res, const float* __restrict__ g,
    const float* __restrict__ bta, bf16_t* __restrict__ x1,
    bf16_t* __restrict__ q2) {
  const int row = blockIdx.x;
  const int tid = threadIdx.x, w = tid >> 6, lane = tid & 63;
  f32x4 v = *(const f32x4*)&res[(size_t)row * 1024 + tid * 4];
  float s = v[0] + v[1] + v[2] + v[3];
  float sq = v[0] * v[0] + v[1] * v[1] + v[2] * v[2] + v[3] * v[3];
#pragma unroll
  for (int off = 32; off >= 1; off >>= 1) {
    s += __shfl_xor(s, off, 64);
    sq += __shfl_xor(sq, off, 64);
  }
  __shared__ float rs[4], rq[4], wtot[4];
  if (lane == 0) {
    rs[w] = s;
    rq[w] = sq;
  }
  __syncthreads();
  s = rs[0] + rs[1] + rs[2] + rs[3];
  sq = rq[0] + rq[1] + rq[2] + rq[3];
  const float mean = s * (1.f / 1024.f);
  const float var = fmaxf(sq * (1.f / 1024.f) - mean * mean, 0.f);
  const float rstd = rsqrtf(var + 1e-5f);

  const f32x4 gv = *(const f32x4*)&g[tid * 4];
  const f32x4 bv = *(const f32x4*)&bta[tid * 4];
  float c[4], p = 1.f;
  u16x4 xb;
#pragma unroll
  for (int i = 0; i < 4; ++i) {
    const float y = (v[i] - mean) * rstd * gv[i] + bv[i];
    const bf16_t yb = (bf16_t)y;
    xb[i] = __builtin_bit_cast(unsigned short, yb);
    c[i] = __cosf((float)yb);
    p *= c[i];
  }
  *(u16x4*)&x1[(size_t)row * 1024 + tid * 4] = xb;

  float ip = p;
#pragma unroll
  for (int off = 1; off < 64; off <<= 1) {
    const float t = __shfl_up(ip, off, 64);
    if (lane >= off) ip *= t;
  }
  if (lane == 63) wtot[w] = ip;
  __syncthreads();
  float carry = 1.f;
  for (int u = 0; u < w; ++u) carry *= wtot[u];
  float run = __shfl_up(ip, 1, 64);
  if (lane == 0) run = 1.f;
  run *= carry;
  u16x4 qv;
#pragma unroll
  for (int i = 0; i < 4; ++i) {
    run *= c[i];
    qv[i] = bf16_bits(run);
  }
  *(u16x4*)&q2[(size_t)row * 1024 + tid * 4] = qv;
}

// ---------------------------------------------------------------------------
// LN2: f32 in, f32 out
// ---------------------------------------------------------------------------
__global__ __launch_bounds__(256) void ln2_kernel(
    const float* __restrict__ res, const float* __restrict__ g,
    const float* __restrict__ bta, float* __restrict__ out) {
  const int row = blockIdx.x;
  const int tid = threadIdx.x, w = tid >> 6, lane = tid & 63;
  f32x4 v = *(const f32x4*)&res[(size_t)row * 1024 + tid * 4];
  float s = v[0] + v[1] + v[2] + v[3];
  float sq = v[0] * v[0] + v[1] * v[1] + v[2] * v[2] + v[3] * v[3];
#pragma unroll
  for (int off = 32; off >= 1; off >>= 1) {
    s += __shfl_xor(s, off, 64);
    sq += __shfl_xor(sq, off, 64);
  }
  __shared__ float rs[4], rq[4];
  if (lane == 0) {
    rs[w] = s;
    rq[w] = sq;
  }
  __syncthreads();
  s = rs[0] + rs[1] + rs[2] + rs[3];
  sq = rq[0] + rq[1] + rq[2] + rq[3];
  const float mean = s * (1.f / 1024.f);
  const float var = fmaxf(sq * (1.f / 1024.f) - mean * mean, 0.f);
  const float rstd = rsqrtf(var + 1e-5f);
  const f32x4 gv = *(const f32x4*)&g[tid * 4];
  const f32x4 bv = *(const f32x4*)&bta[tid * 4];
  f32x4 y;
#pragma unroll
  for (int i = 0; i < 4; ++i) y[i] = (v[i] - mean) * rstd * gv[i] + bv[i];
  *(f32x4*)&out[(size_t)row * 1024 + tid * 4] = y;
}

// ---------------------------------------------------------------------------
extern "C" void kernel_launch(void* const* d_in, const int* in_sizes, int n_in,
                              void* d_out, int out_size, void* d_ws,
                              size_t ws_size, hipStream_t stream) {
  (void)in_sizes;
  (void)n_in;
  (void)out_size;
  (void)ws_size;
  const float* x = (const float*)d_in[0];
  const float* wq = (const float*)d_in[2];
  const float* wk = (const float*)d_in[3];
  const float* wv = (const float*)d_in[4];
  const float* wo = (const float*)d_in[5];
  const float* attn_qw = (const float*)d_in[7];
  const float* w1 = (const float*)d_in[8];
  const float* b1 = (const float*)d_in[9];
  const float* w2 = (const float*)d_in[10];
  const float* b2 = (const float*)d_in[11];
  const float* ffn_qw = (const float*)d_in[13];
  const float* ln1_g = (const float*)d_in[14];
  const float* ln1_b = (const float*)d_in[15];
  const float* ln2_g = (const float*)d_in[16];
  const float* ln2_b = (const float*)d_in[17];

  char* ws = (char*)d_ws;
  char* wsout = (char*)d_out;
  // ws (<=30 MB):
  bf16_t* wT3 = (bf16_t*)(ws + 0);            // [0,6M)  wo|w1|w2 T (persists)
  bf16_t* wqkvT = (bf16_t*)(ws + 6 * MB);     // [6,12M)  dies after QKVVT
  bf16_t* xc = (bf16_t*)(ws + 12 * MB);       // [12,20M) dies after QKVVT
  bf16_t* qb = (bf16_t*)(ws + 20 * MB);       // [20,28M) dies after attn
  bf16_t* aout = (bf16_t*)(ws + 6 * MB);      // [6,14M)  after attn
  float* res = (float*)(ws + 14 * MB);        // [14,30M) after WO
  bf16_t* x1 = (bf16_t*)(ws + 6 * MB);        // [6,14M)  after LN1 (aout dead)
  float* res2 = (float*)(ws + 14 * MB);       // [14,30M)
  // d_out (16 MB) as scratch:
  bf16_t* kb = (bf16_t*)(wsout + 0);          // [0,8M)   dies after attn
  bf16_t* vTb = (bf16_t*)(wsout + 8 * MB);    // [8,16M)  dies after attn
  bf16_t* q2 = (bf16_t*)(wsout + 0);          // [0,8M)   after attn
  bf16_t* hbuf = (bf16_t*)(wsout + 8 * MB);   // [8,16M)  after attn

  const dim3 tb(256);

  prep_kernel<<<8192, tb, 0, stream>>>(x, wq, wk, wv, wo, w1, w2, xc, wqkvT, wT3);

  qkvvt8_kernel<<<192, dim3(512), 0, stream>>>(xc, wqkvT, qb, kb, vTb);

  attn_kernel<<<dim3(16, 32), tb, 0, stream>>>(qb, kb, vTb, attn_qw, aout);

  gemm8_kernel<EPI_WO><<<512, tb, 0, stream>>>(
      aout, wT3, res, x, nullptr, nullptr, nullptr);

  ln1scan_kernel<<<4096, tb, 0, stream>>>(res, ln1_g, ln1_b, x1, q2);

  gemm8_kernel<EPI_W1><<<512, tb, 0, stream>>>(
      x1, wT3 + 1024 * 1024, hbuf, nullptr, q2, b1, ffn_qw);

  gemm8_kernel<EPI_W2><<<512, tb, 0, stream>>>(
      hbuf, wT3 + 2 * 1024 * 1024, res2, nullptr, x1, b2, nullptr);

  ln2_kernel<<<4096, tb, 0, stream>>>(res2, ln2_g, ln2_b, (float*)d_out);
}

// Round 12
// 258.013 us; speedup vs baseline: 1.0348x; 1.0348x over previous
//
#include <hip/hip_runtime.h>
#include <hip/hip_bf16.h>
#include <cmath>
#include <cstdint>

// ---------------------------------------------------------------------------
// QuantumTransformerBlock. Inputs f32, output f32. Internals bf16 MFMA.
// R21 == R19 restored (R20's 3-buffer rotation regressed: runtime-indexed
//      buffer pointer defeated static addressing; vmcnt stall was already
//      TLP-hidden). Session best config:
//      - attn: R11 structure (4 waves x 32 q-rows, QBLK=128, 2 blocks/CU)
//      - qkvvt8: coarse 2-phase 256x256, 8 waves
//      - gemm8: BM=64 x BN=128, 2 blocks/CU, vmcnt(6) 2-phase
//      - prep: vectorized transpose; LN1scan/LN2 f32x4
// ---------------------------------------------------------------------------

typedef __bf16 bf16_t;
typedef __bf16 bf16x8 __attribute__((ext_vector_type(8)));
typedef float f32x4 __attribute__((ext_vector_type(4)));
typedef unsigned short u16x4 __attribute__((ext_vector_type(4)));

#define DEV_INLINE __device__ __forceinline__
#define MB 1048576

DEV_INLINE void gload16(const void* g, void* lds) {
  __builtin_amdgcn_global_load_lds(
      (const __attribute__((address_space(1))) unsigned int*)g,
      (__attribute__((address_space(3))) unsigned int*)lds, 16, 0, 0);
}

DEV_INLINE unsigned short bf16_bits(float f) {
  bf16_t b = (bf16_t)f;
  return __builtin_bit_cast(unsigned short, b);
}

#define BAR_PRE_LGKM asm volatile("s_waitcnt lgkmcnt(0)" ::: "memory")
#define BAR_PRE_VM8 asm volatile("s_waitcnt vmcnt(8)" ::: "memory")
#define BAR_PRE_VM6 asm volatile("s_waitcnt vmcnt(6)" ::: "memory")
#define RAW_BAR                 \
  __builtin_amdgcn_s_barrier(); \
  asm volatile("" ::: "memory")

// ---------------------------------------------------------------------------
// prep: [0,2048) convx  x f32 -> bf16 (f32x4 vector loads)
//       [2048,5120) tconv3 wq|wk|wv -> wqkvT[3072][1024]
//       [5120,8192) tconv3 wo|w1|w2 -> wT3[3072][1024]
// ---------------------------------------------------------------------------
__global__ __launch_bounds__(256) void prep_kernel(
    const float* __restrict__ x, const float* __restrict__ wq,
    const float* __restrict__ wk, const float* __restrict__ wv,
    const float* __restrict__ wo, const float* __restrict__ w1,
    const float* __restrict__ w2, bf16_t* __restrict__ xc,
    bf16_t* __restrict__ wqkvT, bf16_t* __restrict__ wT3) {
  __shared__ bf16_t t[32][36];  // row stride 72B: u16x4 8B-aligned
  const int bid = blockIdx.x;
  if (bid < 2048) {
    const size_t i0 = ((size_t)bid * 256 + threadIdx.x) * 8;
    const f32x4 a = *(const f32x4*)&x[i0];
    const f32x4 b2 = *(const f32x4*)&x[i0 + 4];
    bf16x8 v;
#pragma unroll
    for (int j = 0; j < 4; ++j) {
      v[j] = (bf16_t)a[j];
      v[4 + j] = (bf16_t)b2[j];
    }
    *(bf16x8*)(xc + i0) = v;
    return;
  }
  const int grp = (bid - 2048) / 3072;  // 0 -> wqkvT, 1 -> wT3
  const int tcb = (bid - 2048) - grp * 3072;
  const int mi = tcb >> 10;
  const float* src;
  bf16_t* dst;
  if (grp == 0) {
    src = (mi == 0) ? wq : (mi == 1) ? wk : wv;
    dst = wqkvT;
  } else {
    src = (mi == 0) ? wo : (mi == 1) ? w1 : w2;
    dst = wT3;
  }
  const int rem = tcb & 1023;
  const int bx = (rem & 31) * 32, by = (rem >> 5) * 32;
  const int r = threadIdx.x >> 3, g4 = (threadIdx.x & 7) * 4;

  const f32x4 v4 = *(const f32x4*)&src[(size_t)(by + r) * 1024 + bx + g4];
  u16x4 w4;
#pragma unroll
  for (int e = 0; e < 4; ++e) w4[e] = bf16_bits(v4[e]);
  *(u16x4*)&t[r][g4] = w4;
  __syncthreads();

  u16x4 o4;
#pragma unroll
  for (int e = 0; e < 4; ++e)
    o4[e] = __builtin_bit_cast(unsigned short, t[g4 + e][r]);
  *(u16x4*)&dst[(size_t)(mi * 1024 + bx + r) * 1024 + by + g4] = o4;
}

// ---------------------------------------------------------------------------
// merged QK + VT GEMM, 256x256-tile coarse 2-phase pipeline (R11 version).
// blocks [0,128): QK  C[4096 x 2048] = xc @ (wq|wk)T^T   (16 x 8 tiles)
// blocks [128,192): VT C[1024 x 4096] = wvT @ xc^T       (4 x 16 tiles)
// 512 threads = 8 waves (2M x 4N), per-wave 128x64 output, BK=64.
// Swizzle: logical byte p stored at p ^ (((p>>7)&7)<<4) (involution).
// ---------------------------------------------------------------------------
DEV_INLINE void stage_tile(const char* __restrict__ G, char* ldsT, int k0b,
                           int wid, int lane) {
#pragma unroll
  for (int t = 0; t < 4; ++t) {
    const int plin = t * 8192 + wid * 1024 + lane * 16;
    const int p = plin ^ ((((unsigned)plin >> 7) & 7) << 4);
    gload16(G + (size_t)(p >> 7) * 2048 + k0b + (p & 127),
            ldsT + t * 8192 + wid * 1024);
  }
}

DEV_INLINE void compute_tile(const char* lds_tile, int wm, int wn, int quad,
                             int tc, f32x4 (&acc)[8][4]) {
  const char* Ab = lds_tile;
  const char* Bb = lds_tile + 32768;
#pragma unroll
  for (int ks = 0; ks < 2; ++ks) {
    const int colb = ks * 64 + quad * 16;
    bf16x8 bfv[4];
#pragma unroll
    for (int j = 0; j < 4; ++j) {
      const int r = wn + j * 16 + tc;
      bfv[j] = *(const bf16x8*)(Bb + ((r * 128 + colb) ^ ((r & 7) << 4)));
    }
#pragma unroll
    for (int ih = 0; ih < 2; ++ih) {
      bf16x8 af[4];
#pragma unroll
      for (int i = 0; i < 4; ++i) {
        const int r = wm + (ih * 4 + i) * 16 + tc;
        af[i] = *(const bf16x8*)(Ab + ((r * 128 + colb) ^ ((r & 7) << 4)));
      }
      __builtin_amdgcn_s_setprio(1);
#pragma unroll
      for (int i = 0; i < 4; ++i)
#pragma unroll
        for (int j = 0; j < 4; ++j)
          acc[ih * 4 + i][j] = __builtin_amdgcn_mfma_f32_16x16x32_bf16(
              af[i], bfv[j], acc[ih * 4 + i][j], 0, 0, 0);
      __builtin_amdgcn_s_setprio(0);
    }
  }
}

__global__ __launch_bounds__(512, 2) void qkvvt8_kernel(
    const bf16_t* __restrict__ xc, const bf16_t* __restrict__ wqkvT,
    bf16_t* __restrict__ qb, bf16_t* __restrict__ kb,
    bf16_t* __restrict__ vTb) {
  __shared__ __align__(16) char lds[131072];
  const int tid = threadIdx.x, wid = tid >> 6, lane = tid & 63;
  const int quad = lane >> 4, tc = lane & 15;
  const int bid = blockIdx.x;
  const int isqk = (bid < 128);
  int m0, n0;
  const char *A, *B;
  if (isqk) {
    m0 = (bid >> 3) * 256;
    n0 = (bid & 7) * 256;
    A = (const char*)(xc + (size_t)m0 * 1024);
    B = (const char*)(wqkvT + (size_t)n0 * 1024);
  } else {
    const int t2 = bid - 128;
    m0 = (t2 >> 4) * 256;
    n0 = (t2 & 15) * 256;
    A = (const char*)(wqkvT + (size_t)(2 * 1024 * 1024) + (size_t)m0 * 1024);
    B = (const char*)(xc + (size_t)n0 * 1024);
  }
  const int wm = (wid >> 2) * 128, wn = (wid & 3) * 64;

  f32x4 acc[8][4] = {};

  stage_tile(A, lds, 0, wid, lane);
  stage_tile(B, lds + 32768, 0, wid, lane);
  stage_tile(A, lds + 65536, 128, wid, lane);
  stage_tile(B, lds + 98304, 128, wid, lane);
  BAR_PRE_VM8;
  RAW_BAR;

  for (int it = 0; it < 7; ++it) {
    const int k0b = it * 256 + 256;
    compute_tile(lds, wm, wn, quad, tc, acc);
    BAR_PRE_LGKM;
    RAW_BAR;
    stage_tile(A, lds, k0b, wid, lane);
    stage_tile(B, lds + 32768, k0b, wid, lane);
    BAR_PRE_VM8;
    RAW_BAR;
    compute_tile(lds + 65536, wm, wn, quad, tc, acc);
    BAR_PRE_LGKM;
    RAW_BAR;
    stage_tile(A, lds + 65536, k0b + 128, wid, lane);
    stage_tile(B, lds + 98304, k0b + 128, wid, lane);
    BAR_PRE_VM8;
    RAW_BAR;
  }
  compute_tile(lds, wm, wn, quad, tc, acc);
  asm volatile("s_waitcnt vmcnt(0)" ::: "memory");
  BAR_PRE_LGKM;
  RAW_BAR;
  compute_tile(lds + 65536, wm, wn, quad, tc, acc);

#pragma unroll
  for (int i = 0; i < 8; ++i) {
#pragma unroll
    for (int j = 0; j < 4; ++j) {
      const int row0 = m0 + wm + i * 16 + quad * 4;
      const int col = n0 + wn + j * 16 + tc;
      if (isqk) {
        const int part = col >> 10, e = col & 1023, hh = e >> 6, d = e & 63;
        bf16_t* dst = part ? kb : qb;
#pragma unroll
        for (int r = 0; r < 4; ++r) {
          const int row = row0 + r;
          const int b = row >> 11, s = row & 2047;
          dst[((size_t)(b * 16 + hh) * 2048 + s) * 64 + d] = (bf16_t)acc[i][j][r];
        }
      } else {
        const int b = col >> 11, s = col & 2047;
#pragma unroll
        for (int r = 0; r < 4; ++r) {
          vTb[((size_t)(b * 1024 + row0 + r)) * 2048 + s] = (bf16_t)acc[i][j][r];
        }
      }
    }
  }
}

// ---------------------------------------------------------------------------
// W-GEMM (R19): C[4096,1024] = A[4096,1024] * Bt[1024,1024]^T.
// BM=64, BN=128, BK=64, 256 threads = 4 waves (2x2), per-wave 32x64 output.
// LDS 48KB: 2 buffers x (A 8KB + B 16KB) -> 2 blocks/CU (TLP).
// Ledger: 6 loads/tile; prologue 12 outstanding, vmcnt(6) = buf0 landed;
// steady-state stage 6 then vmcnt(6) = other buf landed.
// Grid 512 = 64 m-tiles x 8 n-tiles, XCD-chunked (512 = 8 x 64).
// ---------------------------------------------------------------------------
enum { EPI_WO = 2, EPI_W1 = 3, EPI_W2 = 4 };

DEV_INLINE void stageA64(const char* __restrict__ G, char* ldsT, int k0b,
                         int tid) {
#pragma unroll
  for (int t = 0; t < 2; ++t) {
    const int plin = t * 4096 + tid * 16;
    const int p = plin ^ ((((unsigned)plin >> 7) & 7) << 4);
    gload16(G + (size_t)(p >> 7) * 2048 + k0b + (p & 127),
            ldsT + t * 4096 + (tid >> 6) * 1024);
  }
}

DEV_INLINE void stageB128(const char* __restrict__ G, char* ldsT, int k0b,
                          int tid) {
#pragma unroll
  for (int t = 0; t < 4; ++t) {
    const int plin = t * 4096 + tid * 16;
    const int p = plin ^ ((((unsigned)plin >> 7) & 7) << 4);
    gload16(G + (size_t)(p >> 7) * 2048 + k0b + (p & 127),
            ldsT + t * 4096 + (tid >> 6) * 1024);
  }
}

DEV_INLINE void compute64(const char* lds_tile, int wm, int wn, int quad,
                          int tc, f32x4 (&acc)[2][4]) {
  const char* Ab = lds_tile;
  const char* Bb = lds_tile + 8192;
#pragma unroll
  for (int ks = 0; ks < 2; ++ks) {
    const int colb = ks * 64 + quad * 16;
    bf16x8 bfv[4];
#pragma unroll
    for (int j = 0; j < 4; ++j) {
      const int r = wn + j * 16 + tc;
      bfv[j] = *(const bf16x8*)(Bb + ((r * 128 + colb) ^ ((r & 7) << 4)));
    }
    bf16x8 af[2];
#pragma unroll
    for (int i = 0; i < 2; ++i) {
      const int r = wm + i * 16 + tc;
      af[i] = *(const bf16x8*)(Ab + ((r * 128 + colb) ^ ((r & 7) << 4)));
    }
    __builtin_amdgcn_s_setprio(1);
#pragma unroll
    for (int i = 0; i < 2; ++i)
#pragma unroll
      for (int j = 0; j < 4; ++j)
        acc[i][j] = __builtin_amdgcn_mfma_f32_16x16x32_bf16(af[i], bfv[j],
                                                            acc[i][j], 0, 0, 0);
    __builtin_amdgcn_s_setprio(0);
  }
}

template <int EPI>
__global__ __launch_bounds__(256, 2) void gemm8_kernel(
    const bf16_t* __restrict__ A, const bf16_t* __restrict__ Bt,
    void* __restrict__ o0, const float* __restrict__ auxf,
    const bf16_t* __restrict__ auxb, const float* __restrict__ bias,
    const float* __restrict__ scal) {
  __shared__ __align__(16) char lds[49152];
  const int tid = threadIdx.x, wid = tid >> 6, lane = tid & 63;
  const int quad = lane >> 4, tc = lane & 15;
  const int bid = blockIdx.x;
  const int g = (bid & 7) * 64 + (bid >> 3);  // XCD-chunked tile id
  const int m0 = (g >> 3) * 64, n0 = (g & 7) * 128;
  const char* Ag = (const char*)A + (size_t)m0 * 2048;
  const char* Bg = (const char*)Bt + (size_t)n0 * 2048;
  const int wm = (wid >> 1) * 32, wn = (wid & 1) * 64;

  f32x4 acc[2][4] = {};

  // buffers: buf0 @0 (A 8KB + B 16KB), buf1 @24KB
  stageA64(Ag, lds, 0, tid);
  stageB128(Bg, lds + 8192, 0, tid);
  stageA64(Ag, lds + 24576, 128, tid);
  stageB128(Bg, lds + 32768, 128, tid);
  BAR_PRE_VM6;  // 12 issued, <=6 outstanding -> buf0's 6 landed
  RAW_BAR;

  for (int it = 0; it < 7; ++it) {
    const int k0b = it * 256 + 256;
    compute64(lds, wm, wn, quad, tc, acc);
    BAR_PRE_LGKM;
    RAW_BAR;  // buf0 free
    stageA64(Ag, lds, k0b, tid);
    stageB128(Bg, lds + 8192, k0b, tid);
    BAR_PRE_VM6;  // buf1's 6 landed (buf0-next 6 in flight)
    RAW_BAR;
    compute64(lds + 24576, wm, wn, quad, tc, acc);
    BAR_PRE_LGKM;
    RAW_BAR;  // buf1 free
    stageA64(Ag, lds + 24576, k0b + 128, tid);
    stageB128(Bg, lds + 32768, k0b + 128, tid);
    BAR_PRE_VM6;
    RAW_BAR;
  }
  compute64(lds, wm, wn, quad, tc, acc);
  asm volatile("s_waitcnt vmcnt(0)" ::: "memory");
  BAR_PRE_LGKM;
  RAW_BAR;
  compute64(lds + 24576, wm, wn, quad, tc, acc);

  float wsig = 0.f;
  if (EPI == EPI_W1) wsig = 1.f / (1.f + __expf(-scal[0]));

#pragma unroll
  for (int i = 0; i < 2; ++i) {
#pragma unroll
    for (int j = 0; j < 4; ++j) {
      const int row0 = m0 + wm + i * 16 + quad * 4;
      const int col = n0 + wn + j * 16 + tc;
      if (EPI == EPI_WO) {
#pragma unroll
        for (int r = 0; r < 4; ++r) {
          const int row = row0 + r;
          ((float*)o0)[(size_t)row * 1024 + col] =
              acc[i][j][r] + auxf[(size_t)row * 1024 + col];
        }
      } else if (EPI == EPI_W1) {
#pragma unroll
        for (int r = 0; r < 4; ++r) {
          const int row = row0 + r;
          float c = fmaxf(acc[i][j][r] + bias[col], 0.f);
          const float qv = (float)auxb[(size_t)row * 1024 + col];
          ((bf16_t*)o0)[(size_t)row * 1024 + col] =
              (bf16_t)(wsig * qv + (1.f - wsig) * c);
        }
      } else {  // EPI_W2
#pragma unroll
        for (int r = 0; r < 4; ++r) {
          const int row = row0 + r;
          ((float*)o0)[(size_t)row * 1024 + col] =
              acc[i][j][r] + bias[col] + (float)auxb[(size_t)row * 1024 + col];
        }
      }
    }
  }
}

// ---------------------------------------------------------------------------
// Flash attention (R11 structure): q-tile 128/block, 4 waves x 32 q-rows
// (2 subtiles). Register-prefetch K/V staging; exp2 softmax (no-max);
// S^T = K*Q^T; wave-local Ps. LDS strides 72.
// ---------------------------------------------------------------------------
__global__ __launch_bounds__(256) void attn_kernel(
    const bf16_t* __restrict__ q, const bf16_t* __restrict__ k,
    const bf16_t* __restrict__ vT, const float* __restrict__ aqw,
    bf16_t* __restrict__ out) {
  constexpr int S = 2048, LDK = 72;
  __shared__ __align__(16) bf16_t Ks[64 * LDK];
  __shared__ __align__(16) bf16_t Vs[64 * LDK];
  __shared__ __align__(16) bf16_t Ps[4][32 * LDK];
  __shared__ bf16_t Ql[128 * LDK];
  __shared__ float segp[128][4];

  const int tid = threadIdx.x, w = tid >> 6, lane = tid & 63;
  const int quad = lane >> 4, tc = lane & 15;
  const int bh = blockIdx.y, q0 = blockIdx.x * 128;
  const bf16_t* qg = q + ((size_t)bh * S + q0) * 64;
  const bf16_t* kg = k + (size_t)bh * S * 64;
  const bf16_t* vg = vT + (size_t)bh * 64 * S;

  const int strow = tid >> 2, stcol = (tid & 3) * 16;

  bf16x8 pk0 = *(const bf16x8*)(kg + (size_t)strow * 64 + stcol);
  bf16x8 pk1 = *(const bf16x8*)(kg + (size_t)strow * 64 + stcol + 8);
  bf16x8 pv0 = *(const bf16x8*)(vg + (size_t)strow * S + stcol);
  bf16x8 pv1 = *(const bf16x8*)(vg + (size_t)strow * S + stcol + 8);

  // quantum: cumprod(cos(q)) for 128 rows; 4 threads/row, 2 passes
  {
    float c[2][16];
    const int ss = tid & 3;
#pragma unroll
    for (int pass = 0; pass < 2; ++pass) {
      const int rr = pass * 64 + (tid >> 2);
      const bf16_t* qr = qg + rr * 64 + ss * 16;
      float p = 1.f;
#pragma unroll
      for (int j2 = 0; j2 < 16; ++j2) {
        c[pass][j2] = __cosf((float)qr[j2]);
        p *= c[pass][j2];
      }
      segp[rr][ss] = p;
    }
    __syncthreads();
#pragma unroll
    for (int pass = 0; pass < 2; ++pass) {
      const int rr = pass * 64 + (tid >> 2);
      float pre = 1.f;
      for (int u = 0; u < ss; ++u) pre *= segp[rr][u];
#pragma unroll
      for (int j2 = 0; j2 < 16; ++j2) {
        pre *= c[pass][j2];
        Ql[rr * LDK + ss * 16 + j2] = (bf16_t)pre;
      }
    }
  }

  bf16x8 aq[2][2];
#pragma unroll
  for (int qs = 0; qs < 2; ++qs) {
    const int qrow = w * 32 + qs * 16 + tc;
#pragma unroll
    for (int ks = 0; ks < 2; ++ks) {
      bf16x8 t = *(const bf16x8*)(qg + qrow * 64 + ks * 32 + quad * 8);
#pragma unroll
      for (int e = 0; e < 8; ++e) t[e] = (bf16_t)((float)t[e] * 0.18033688f);
      aq[qs][ks] = t;
    }
  }

  float lacc[2] = {0.f, 0.f};
  f32x4 o[2][4] = {};
  bf16_t* Pw = Ps[w];

  for (int kt = 0; kt < S; kt += 64) {
    __syncthreads();
    *(bf16x8*)&Ks[strow * LDK + stcol] = pk0;
    *(bf16x8*)&Ks[strow * LDK + stcol + 8] = pk1;
    *(bf16x8*)&Vs[strow * LDK + stcol] = pv0;
    *(bf16x8*)&Vs[strow * LDK + stcol + 8] = pv1;
    if (kt + 64 < S) {
      const int nk = kt + 64;
      pk0 = *(const bf16x8*)(kg + (size_t)(nk + strow) * 64 + stcol);
      pk1 = *(const bf16x8*)(kg + (size_t)(nk + strow) * 64 + stcol + 8);
      pv0 = *(const bf16x8*)(vg + (size_t)strow * S + nk + stcol);
      pv1 = *(const bf16x8*)(vg + (size_t)strow * S + nk + stcol + 8);
    }
    __syncthreads();

    f32x4 sf[2][4] = {};
#pragma unroll
    for (int ks = 0; ks < 2; ++ks) {
#pragma unroll
      for (int nt = 0; nt < 4; ++nt) {
        bf16x8 ak = *(const bf16x8*)&Ks[(nt * 16 + tc) * LDK + ks * 32 + quad * 8];
        sf[0][nt] = __builtin_amdgcn_mfma_f32_16x16x32_bf16(ak, aq[0][ks], sf[0][nt], 0, 0, 0);
        sf[1][nt] = __builtin_amdgcn_mfma_f32_16x16x32_bf16(ak, aq[1][ks], sf[1][nt], 0, 0, 0);
      }
    }

#pragma unroll
    for (int qs = 0; qs < 2; ++qs) {
#pragma unroll
      for (int nt = 0; nt < 4; ++nt) {
        u16x4 pk;
        float ps = 0.f;
#pragma unroll
        for (int r = 0; r < 4; ++r) {
          const float p = __builtin_amdgcn_exp2f(sf[qs][nt][r]);
          ps += p;
          pk[r] = bf16_bits(p);
        }
        lacc[qs] += ps;
        *(u16x4*)&Pw[(qs * 16 + tc) * LDK + nt * 16 + quad * 4] = pk;
      }
    }
    asm volatile("s_waitcnt lgkmcnt(0)" ::: "memory");

#pragma unroll
    for (int ks = 0; ks < 2; ++ks) {
      bf16x8 ap0 = *(const bf16x8*)&Pw[tc * LDK + ks * 32 + quad * 8];
      bf16x8 ap1 = *(const bf16x8*)&Pw[(16 + tc) * LDK + ks * 32 + quad * 8];
#pragma unroll
      for (int j = 0; j < 4; ++j) {
        bf16x8 bv = *(const bf16x8*)&Vs[(j * 16 + tc) * LDK + ks * 32 + quad * 8];
        o[0][j] = __builtin_amdgcn_mfma_f32_16x16x32_bf16(ap0, bv, o[0][j], 0, 0, 0);
        o[1][j] = __builtin_amdgcn_mfma_f32_16x16x32_bf16(ap1, bv, o[1][j], 0, 0, 0);
      }
    }
  }

#pragma unroll
  for (int qs = 0; qs < 2; ++qs) {
    lacc[qs] += __shfl_xor(lacc[qs], 16, 64);
    lacc[qs] += __shfl_xor(lacc[qs], 32, 64);
  }

  const float wsig = 1.f / (1.f + __expf(-aqw[0]));
  const int b = bh >> 4, h = bh & 15;
#pragma unroll
  for (int qs = 0; qs < 2; ++qs) {
#pragma unroll
    for (int r = 0; r < 4; ++r) {
      const int lr = quad * 4 + r;
      const float linv = 1.f / __shfl(lacc[qs], lr, 64);
      const int lrow = w * 32 + qs * 16 + lr;
      const int sg = q0 + lrow;
#pragma unroll
      for (int j = 0; j < 4; ++j) {
        const int d = j * 16 + tc;
        const float cl = o[qs][j][r] * linv;
        const float qv = (float)Ql[lrow * LDK + d];
        out[((size_t)(b * 2048 + sg)) * 1024 + h * 64 + d] =
            (bf16_t)(wsig * qv + (1.f - wsig) * cl);
      }
    }
  }
}

// ---------------------------------------------------------------------------
// LN1 + cumprod-scan fused: one block per row.
// ---------------------------------------------------------------------------
__global__ __launch_bounds__(256) void ln1scan_kernel(
    const float* __restrict__ res, const float* __restrict__ g,
    const float* __restrict__ bta, bf16_t* __restrict__ x1,
    bf16_t* __restrict__ q2) {
  const int row = blockIdx.x;
  const int tid = threadIdx.x, w = tid >> 6, lane = tid & 63;
  f32x4 v = *(const f32x4*)&res[(size_t)row * 1024 + tid * 4];
  float s = v[0] + v[1] + v[2] + v[3];
  float sq = v[0] * v[0] + v[1] * v[1] + v[2] * v[2] + v[3] * v[3];
#pragma unroll
  for (int off = 32; off >= 1; off >>= 1) {
    s += __shfl_xor(s, off, 64);
    sq += __shfl_xor(sq, off, 64);
  }
  __shared__ float rs[4], rq[4], wtot[4];
  if (lane == 0) {
    rs[w] = s;
    rq[w] = sq;
  }
  __syncthreads();
  s = rs[0] + rs[1] + rs[2] + rs[3];
  sq = rq[0] + rq[1] + rq[2] + rq[3];
  const float mean = s * (1.f / 1024.f);
  const float var = fmaxf(sq * (1.f / 1024.f) - mean * mean, 0.f);
  const float rstd = rsqrtf(var + 1e-5f);

  const f32x4 gv = *(const f32x4*)&g[tid * 4];
  const f32x4 bv = *(const f32x4*)&bta[tid * 4];
  float c[4], p = 1.f;
  u16x4 xb;
#pragma unroll
  for (int i = 0; i < 4; ++i) {
    const float y = (v[i] - mean) * rstd * gv[i] + bv[i];
    const bf16_t yb = (bf16_t)y;
    xb[i] = __builtin_bit_cast(unsigned short, yb);
    c[i] = __cosf((float)yb);
    p *= c[i];
  }
  *(u16x4*)&x1[(size_t)row * 1024 + tid * 4] = xb;

  float ip = p;
#pragma unroll
  for (int off = 1; off < 64; off <<= 1) {
    const float t = __shfl_up(ip, off, 64);
    if (lane >= off) ip *= t;
  }
  if (lane == 63) wtot[w] = ip;
  __syncthreads();
  float carry = 1.f;
  for (int u = 0; u < w; ++u) carry *= wtot[u];
  float run = __shfl_up(ip, 1, 64);
  if (lane == 0) run = 1.f;
  run *= carry;
  u16x4 qv;
#pragma unroll
  for (int i = 0; i < 4; ++i) {
    run *= c[i];
    qv[i] = bf16_bits(run);
  }
  *(u16x4*)&q2[(size_t)row * 1024 + tid * 4] = qv;
}

// ---------------------------------------------------------------------------
// LN2: f32 in, f32 out
// ---------------------------------------------------------------------------
__global__ __launch_bounds__(256) void ln2_kernel(
    const float* __restrict__ res, const float* __restrict__ g,
    const float* __restrict__ bta, float* __restrict__ out) {
  const int row = blockIdx.x;
  const int tid = threadIdx.x, w = tid >> 6, lane = tid & 63;
  f32x4 v = *(const f32x4*)&res[(size_t)row * 1024 + tid * 4];
  float s = v[0] + v[1] + v[2] + v[3];
  float sq = v[0] * v[0] + v[1] * v[1] + v[2] * v[2] + v[3] * v[3];
#pragma unroll
  for (int off = 32; off >= 1; off >>= 1) {
    s += __shfl_xor(s, off, 64);
    sq += __shfl_xor(sq, off, 64);
  }
  __shared__ float rs[4], rq[4];
  if (lane == 0) {
    rs[w] = s;
    rq[w] = sq;
  }
  __syncthreads();
  s = rs[0] + rs[1] + rs[2] + rs[3];
  sq = rq[0] + rq[1] + rq[2] + rq[3];
  const float mean = s * (1.f / 1024.f);
  const float var = fmaxf(sq * (1.f / 1024.f) - mean * mean, 0.f);
  const float rstd = rsqrtf(var + 1e-5f);
  const f32x4 gv = *(const f32x4*)&g[tid * 4];
  const f32x4 bv = *(const f32x4*)&bta[tid * 4];
  f32x4 y;
#pragma unroll
  for (int i = 0; i < 4; ++i) y[i] = (v[i] - mean) * rstd * gv[i] + bv[i];
  *(f32x4*)&out[(size_t)row * 1024 + tid * 4] = y;
}

// ---------------------------------------------------------------------------
extern "C" void kernel_launch(void* const* d_in, const int* in_sizes, int n_in,
                              void* d_out, int out_size, void* d_ws,
                              size_t ws_size, hipStream_t stream) {
  (void)in_sizes;
  (void)n_in;
  (void)out_size;
  (void)ws_size;
  const float* x = (const float*)d_in[0];
  const float* wq = (const float*)d_in[2];
  const float* wk = (const float*)d_in[3];
  const float* wv = (const float*)d_in[4];
  const float* wo = (const float*)d_in[5];
  const float* attn_qw = (const float*)d_in[7];
  const float* w1 = (const float*)d_in[8];
  const float* b1 = (const float*)d_in[9];
  const float* w2 = (const float*)d_in[10];
  const float* b2 = (const float*)d_in[11];
  const float* ffn_qw = (const float*)d_in[13];
  const float* ln1_g = (const float*)d_in[14];
  const float* ln1_b = (const float*)d_in[15];
  const float* ln2_g = (const float*)d_in[16];
  const float* ln2_b = (const float*)d_in[17];

  char* ws = (char*)d_ws;
  char* wsout = (char*)d_out;
  // ws (<=30 MB):
  bf16_t* wT3 = (bf16_t*)(ws + 0);            // [0,6M)  wo|w1|w2 T (persists)
  bf16_t* wqkvT = (bf16_t*)(ws + 6 * MB);     // [6,12M)  dies after QKVVT
  bf16_t* xc = (bf16_t*)(ws + 12 * MB);       // [12,20M) dies after QKVVT
  bf16_t* qb = (bf16_t*)(ws + 20 * MB);       // [20,28M) dies after attn
  bf16_t* aout = (bf16_t*)(ws + 6 * MB);      // [6,14M)  after attn
  float* res = (float*)(ws + 14 * MB);        // [14,30M) after WO
  bf16_t* x1 = (bf16_t*)(ws + 6 * MB);        // [6,14M)  after LN1 (aout dead)
  float* res2 = (float*)(ws + 14 * MB);       // [14,30M)
  // d_out (16 MB) as scratch:
  bf16_t* kb = (bf16_t*)(wsout + 0);          // [0,8M)   dies after attn
  bf16_t* vTb = (bf16_t*)(wsout + 8 * MB);    // [8,16M)  dies after attn
  bf16_t* q2 = (bf16_t*)(wsout + 0);          // [0,8M)   after attn
  bf16_t* hbuf = (bf16_t*)(wsout + 8 * MB);   // [8,16M)  after attn

  const dim3 tb(256);

  prep_kernel<<<8192, tb, 0, stream>>>(x, wq, wk, wv, wo, w1, w2, xc, wqkvT, wT3);

  qkvvt8_kernel<<<192, dim3(512), 0, stream>>>(xc, wqkvT, qb, kb, vTb);

  attn_kernel<<<dim3(16, 32), tb, 0, stream>>>(qb, kb, vTb, attn_qw, aout);

  gemm8_kernel<EPI_WO><<<512, tb, 0, stream>>>(
      aout, wT3, res, x, nullptr, nullptr, nullptr);

  ln1scan_kernel<<<4096, tb, 0, stream>>>(res, ln1_g, ln1_b, x1, q2);

  gemm8_kernel<EPI_W1><<<512, tb, 0, stream>>>(
      x1, wT3 + 1024 * 1024, hbuf, nullptr, q2, b1, ffn_qw);

  gemm8_kernel<EPI_W2><<<512, tb, 0, stream>>>(
      hbuf, wT3 + 2 * 1024 * 1024, res2, nullptr, x1, b2, nullptr);

  ln2_kernel<<<4096, tb, 0, stream>>>(res2, ln2_g, ln2_b, (float*)d_out);
}